// Round 2
// baseline (449.389 us; speedup 1.0000x reference)
//
#include <hip/hip_runtime.h>

// SlideMean_Norm: out[b,0,t,f] = x[b,0,t,f] - mean(x[b,0,s:e,f]),
//   s = max(t-150, 0), e = min(t+150, T-1) (end-exclusive).
// Streaming sliding-window sum in registers, float2 columns.
// R2: VGPR_Count=44 proved the compiler serialized the "batched" loads
//     (30 in-flight float2 need 60 dest VGPRs). Fixes:
//     - __launch_bounds__(64, 1): unlock register budget (only 5 waves/CU
//       resident anyway; the 44-VGPR cap bought nothing).
//     - batch 25 rows/round (75 loads in flight, ~150 data VGPRs).
//     - non-temporal stores: output is write-once; keep it out of L2/L3 so
//       the 288MB-distance lead->center->trail reuse stays L3-resident.

constexpr int B    = 32;
constexpr int T    = 16000;
constexpr int F    = 80;
constexpr int HALF = 150;          // WIN_LEN / 2
constexpr int CL   = 250;          // chunk length along t
constexpr int NCHUNK = T / CL;     // 64
constexpr int RS   = F / 2;        // row stride in float2 units = 40
constexpr int NCOL2 = B * F / 2;   // 1280 float2-columns (multiple of 64)
constexpr int NTHREADS = NCOL2 * NCHUNK;  // 81920
constexpr int BLOCK = 64;
constexpr int BT    = 25;          // rows per round (75 loads in flight)

__device__ __forceinline__ void nt_store2(float2* p, float2 v) {
    union { float2 f; unsigned long long u; } cvt;
    cvt.f = v;
    __builtin_nontemporal_store(cvt.u, (unsigned long long*)p);
}

__global__ __launch_bounds__(BLOCK, 1) void slide_mean_norm(const float2* __restrict__ x,
                                                            float2* __restrict__ out) {
    int tid   = blockIdx.x * BLOCK + threadIdx.x;
    int col2  = tid % NCOL2;        // consecutive lanes -> consecutive float2 (coalesced)
    int chunk = tid / NCOL2;        // wave-uniform
    int b  = col2 / RS;
    int f2 = col2 % RS;

    const float2* xp = x   + (size_t)b * T * RS + f2;
    float2*       op = out + (size_t)b * T * RS + f2;

    int t0 = chunk * CL;
    float sx = 0.f, sy = 0.f;

    bool interior = (t0 >= HALF) && (t0 + CL - 1 + HALF <= T - 1);

    if (interior) {
        // ---- warm-up: exactly 300 rows [t0-150, t0+150), batches of 25 ----
        const float2* p = xp + (t0 - HALF) * RS;
        #pragma unroll 1
        for (int k = 0; k < 2 * HALF; k += BT) {
            float2 v[BT];
            #pragma unroll
            for (int j = 0; j < BT; ++j) v[j] = p[(k + j) * RS];
            #pragma unroll
            for (int j = 0; j < BT; ++j) { sx += v[j].x; sy += v[j].y; }
        }
        // ---- main: branchless, count == 300, 25 iters/round (75 loads in flight) ----
        const float inv = 1.0f / (2.0f * HALF);
        #pragma unroll 1
        for (int i = t0; i < t0 + CL; i += BT) {
            const float2* pc = xp + i * RS;
            const float2* pl = pc + HALF * RS;
            const float2* pt = pc - HALF * RS;
            float2 c[BT], ld[BT], tr[BT];
            #pragma unroll
            for (int j = 0; j < BT; ++j) {
                c[j]  = pc[j * RS];
                ld[j] = pl[j * RS];
                tr[j] = pt[j * RS];
            }
            #pragma unroll
            for (int j = 0; j < BT; ++j) {
                float ox = c[j].x - sx * inv;
                float oy = c[j].y - sy * inv;
                sx += ld[j].x - tr[j].x;
                sy += ld[j].y - tr[j].y;
                nt_store2(&op[(i + j) * RS], make_float2(ox, oy));
            }
        }
    } else {
        // ---- edge chunks (0 and 63): batched + masked, same pipeline shape ----
        int s0 = t0 - HALF; if (s0 < 0) s0 = 0;
        int e0 = t0 + HALF; if (e0 > T - 1) e0 = T - 1;
        int k = s0;
        #pragma unroll 1
        for (; k + BT <= e0; k += BT) {
            float2 v[BT];
            #pragma unroll
            for (int j = 0; j < BT; ++j) v[j] = xp[(k + j) * RS];
            #pragma unroll
            for (int j = 0; j < BT; ++j) { sx += v[j].x; sy += v[j].y; }
        }
        #pragma unroll 1
        for (; k < e0; ++k) { float2 v = xp[k * RS]; sx += v.x; sy += v.y; }

        // main: clamped addresses, 0/1 mask multiplies, per-row 1/(e-s)
        #pragma unroll 1
        for (int i = t0; i < t0 + CL; i += BT) {
            float2 c[BT], ld[BT], tr[BT];
            #pragma unroll
            for (int j = 0; j < BT; ++j) {
                int t = i + j;
                int lidx = t + HALF;
                if (lidx > T - 1) lidx = T - 1;  // clamp: load stays in-bounds
                int tidx = t - HALF;
                if (tidx < 0) tidx = 0;
                c[j]  = xp[t * RS];
                ld[j] = xp[lidx * RS];
                tr[j] = xp[tidx * RS];
            }
            #pragma unroll
            for (int j = 0; j < BT; ++j) {
                int t = i + j;
                int s = t - HALF; if (s < 0) s = 0;
                int e = t + HALF; if (e > T - 1) e = T - 1;
                float inv = 1.0f / (float)(e - s);
                float lm = (t + HALF <= T - 2) ? 1.0f : 0.0f;  // add x[t+150] iff in range
                float tm = (t >= HALF) ? 1.0f : 0.0f;          // sub x[t-150] iff in range
                float ox = c[j].x - sx * inv;
                float oy = c[j].y - sy * inv;
                sx += lm * ld[j].x - tm * tr[j].x;
                sy += lm * ld[j].y - tm * tr[j].y;
                nt_store2(&op[t * RS], make_float2(ox, oy));
            }
        }
    }
}

extern "C" void kernel_launch(void* const* d_in, const int* in_sizes, int n_in,
                              void* d_out, int out_size, void* d_ws, size_t ws_size,
                              hipStream_t stream) {
    const float2* x = (const float2*)d_in[0];
    float2* out = (float2*)d_out;
    slide_mean_norm<<<dim3(NTHREADS / BLOCK), dim3(BLOCK), 0, stream>>>(x, out);
}

// Round 3
// 361.973 us; speedup vs baseline: 1.2415x; 1.2415x over previous
//
#include <hip/hip_runtime.h>

// SlideMean_Norm: out[b,0,t,f] = x[b,0,t,f] - mean(x[b,0,s:e,f]),
//   s = max(t-150, 0), e = min(t+150, T-1) (end-exclusive).
// R3: explicit two-stage software pipeline. R2 proved (VGPR=64) that the
//     compiler contracts hand-batched loads back to shallow sub-batches with
//     full vmcnt drains. Now stage r+1's 30 loads are issued BEFORE stage r
//     is consumed (A/B register double-buffer + sched_barrier(0) pins), so
//     every wait is a counted vmcnt and the memory pipe never drains.
//     amdgpu_waves_per_eu(1,2) relaxes the register target to 256 VGPRs
//     (we only need 5 waves/CU = 1.25/EU resident).
//     Trail loads are non-temporal (last touch of each line).

constexpr int B    = 32;
constexpr int T    = 16000;
constexpr int F    = 80;
constexpr int HALF = 150;          // WIN_LEN / 2
constexpr int CL   = 250;          // chunk length along t
constexpr int NCHUNK = T / CL;     // 64
constexpr int RS   = F / 2;        // row stride in float2 units = 40
constexpr int NCOL2 = B * F / 2;   // 1280 float2-columns
constexpr int NTHREADS = NCOL2 * NCHUNK;  // 81920 -> 1280 waves, 5/CU exact
constexpr int BLOCK = 64;
constexpr int BT    = 10;          // rows per main pipeline stage (30 loads)
constexpr int NST   = CL / BT;     // 25 stages
constexpr int WB    = 25;          // rows per warm-up stage (12 stages)

__device__ __forceinline__ void nt_store2(float2* p, float2 v) {
    union { float2 f; unsigned long long u; } c; c.f = v;
    __builtin_nontemporal_store(c.u, (unsigned long long*)p);
}
__device__ __forceinline__ float2 nt_load2(const float2* p) {
    union { unsigned long long u; float2 f; } c;
    c.u = __builtin_nontemporal_load((const unsigned long long*)p);
    return c.f;
}

__global__ __launch_bounds__(BLOCK)
__attribute__((amdgpu_waves_per_eu(1, 2)))
void slide_mean_norm(const float2* __restrict__ x, float2* __restrict__ out) {
    int tid   = blockIdx.x * BLOCK + threadIdx.x;
    int col2  = tid % NCOL2;        // consecutive lanes -> consecutive float2
    int chunk = tid / NCOL2;        // wave-uniform
    int b  = col2 / RS;
    int f2 = col2 % RS;

    const float2* xp = x   + (size_t)b * T * RS + f2;
    float2*       op = out + (size_t)b * T * RS + f2;

    int t0 = chunk * CL;
    float sx = 0.f, sy = 0.f;

    bool interior = (t0 >= HALF) && (t0 + CL - 1 + HALF <= T - 1);

    if (interior) {
        // ---- warm-up: 300 rows [t0-150, t0+150), 12 pipelined stages of 25 ----
        const float2* wp = xp + (size_t)(t0 - HALF) * RS;
        float2 wA[WB], wB[WB];
        #define WLOAD(buf, s) { const float2* p = wp + (size_t)(s) * WB * RS;       \
            _Pragma("unroll") for (int j = 0; j < WB; ++j) buf[j] = p[j * RS];      \
            __builtin_amdgcn_sched_barrier(0); }
        #define WSUM(buf) { _Pragma("unroll")                                        \
            for (int j = 0; j < WB; ++j) { sx += buf[j].x; sy += buf[j].y; } }
        WLOAD(wA, 0)
        #pragma unroll 1
        for (int r = 0; r < 10; r += 2) {
            WLOAD(wB, r + 1)
            WSUM(wA)
            WLOAD(wA, r + 2)
            WSUM(wB)
        }
        WLOAD(wB, 11)
        WSUM(wA)
        WSUM(wB)

        // ---- main: 25 pipelined stages of 10 rows (30 loads/stage) ----
        const float inv = 1.0f / (2.0f * HALF);
        float2 cA[BT], lA[BT], tA[BT], cB[BT], lB[BT], tB[BT];
        #define MLOAD(ca, la, ta, s) {                                              \
            const float2* pc = xp + (size_t)(t0 + (s) * BT) * RS;                   \
            const float2* pl = pc + HALF * RS;                                      \
            const float2* pt = pc - HALF * RS;                                      \
            _Pragma("unroll") for (int j = 0; j < BT; ++j) {                        \
                ca[j] = pc[j * RS]; la[j] = pl[j * RS]; ta[j] = nt_load2(pt + j * RS); } \
            __builtin_amdgcn_sched_barrier(0); }
        #define MCONS(ca, la, ta, s) {                                              \
            float2* po = op + (size_t)(t0 + (s) * BT) * RS;                         \
            _Pragma("unroll") for (int j = 0; j < BT; ++j) {                        \
                nt_store2(po + j * RS, make_float2(ca[j].x - sx * inv,              \
                                                   ca[j].y - sy * inv));            \
                sx += la[j].x - ta[j].x; sy += la[j].y - ta[j].y; } }
        MLOAD(cA, lA, tA, 0)
        #pragma unroll 1
        for (int r = 0; r < NST - 1; r += 2) {   // r = 0,2,...,22
            MLOAD(cB, lB, tB, r + 1)
            MCONS(cA, lA, tA, r)
            MLOAD(cA, lA, tA, r + 2)
            MCONS(cB, lB, tB, r + 1)
        }
        MCONS(cA, lA, tA, NST - 1)
    } else {
        // ---- edge chunks (0, 63): identical pipeline, clamped + masked ----
        float2 wA[WB], wB[WB];
        #define EWLOAD(buf, s) { int kb = t0 - HALF + (s) * WB;                     \
            _Pragma("unroll") for (int j = 0; j < WB; ++j) {                        \
                int k = kb + j; int kc = k < 0 ? 0 : k;                             \
                buf[j] = xp[(size_t)kc * RS]; }                                     \
            __builtin_amdgcn_sched_barrier(0); }
        #define EWSUM(buf, s) { int kb = t0 - HALF + (s) * WB;                      \
            _Pragma("unroll") for (int j = 0; j < WB; ++j) {                        \
                float m = (kb + j >= 0) ? 1.f : 0.f;                                \
                sx += m * buf[j].x; sy += m * buf[j].y; } }
        EWLOAD(wA, 0)
        #pragma unroll 1
        for (int r = 0; r < 10; r += 2) {
            EWLOAD(wB, r + 1)
            EWSUM(wA, r)
            EWLOAD(wA, r + 2)
            EWSUM(wB, r + 1)
        }
        EWLOAD(wB, 11)
        EWSUM(wA, 10)
        EWSUM(wB, 11)

        float2 cA[BT], lA[BT], tA[BT], cB[BT], lB[BT], tB[BT];
        #define ELOAD(ca, la, ta, s) { int ib = t0 + (s) * BT;                      \
            _Pragma("unroll") for (int j = 0; j < BT; ++j) {                        \
                int t = ib + j;                                                     \
                int li = t + HALF; li = li > T - 1 ? T - 1 : li;                    \
                int ti = t - HALF; ti = ti < 0 ? 0 : ti;                            \
                ca[j] = xp[(size_t)t * RS];                                         \
                la[j] = xp[(size_t)li * RS];                                        \
                ta[j] = xp[(size_t)ti * RS]; }                                      \
            __builtin_amdgcn_sched_barrier(0); }
        #define ECONS(ca, la, ta, s) { int ib = t0 + (s) * BT;                      \
            _Pragma("unroll") for (int j = 0; j < BT; ++j) {                        \
                int t = ib + j;                                                     \
                int ss = t - HALF; ss = ss < 0 ? 0 : ss;                            \
                int ee = t + HALF; ee = ee > T - 1 ? T - 1 : ee;                    \
                float invc = 1.0f / (float)(ee - ss);                               \
                float lm = (t + HALF <= T - 2) ? 1.f : 0.f;                         \
                float tm = (t >= HALF) ? 1.f : 0.f;                                 \
                nt_store2(op + (size_t)t * RS, make_float2(ca[j].x - sx * invc,     \
                                                           ca[j].y - sy * invc));   \
                sx += lm * la[j].x - tm * ta[j].x;                                  \
                sy += lm * la[j].y - tm * ta[j].y; } }
        ELOAD(cA, lA, tA, 0)
        #pragma unroll 1
        for (int r = 0; r < NST - 1; r += 2) {
            ELOAD(cB, lB, tB, r + 1)
            ECONS(cA, lA, tA, r)
            ELOAD(cA, lA, tA, r + 2)
            ECONS(cB, lB, tB, r + 1)
        }
        ECONS(cA, lA, tA, NST - 1)
    }
}

extern "C" void kernel_launch(void* const* d_in, const int* in_sizes, int n_in,
                              void* d_out, int out_size, void* d_ws, size_t ws_size,
                              hipStream_t stream) {
    const float2* x = (const float2*)d_in[0];
    float2* out = (float2*)d_out;
    slide_mean_norm<<<dim3(NTHREADS / BLOCK), dim3(BLOCK), 0, stream>>>(x, out);
}

// Round 4
// 344.057 us; speedup vs baseline: 1.3061x; 1.0521x over previous
//
#include <hip/hip_runtime.h>

// SlideMean_Norm: out[b,0,t,f] = x[b,0,t,f] - mean(x[b,0,s:e,f]),
//   s = max(t-150, 0), e = min(t+150, T-1) (end-exclusive).
// R4: CL 250 -> 500 (64 -> 32 chunks, 1280 -> 640 waves). R3's FETCH=400MB
//     showed L3 evicting re-reads: inter-use flow at 1280 waves x 3 streams
//     x 150 iters = 295 MB > 256 MB L3 (bistable, stuck in all-miss).
//     At 640 waves the flow is 147 MB < L3 -> lead->center re-reads hit,
//     flow collapses to ~49 MB -> trail hits too. Warm-up overhead also
//     halves. MLP still sufficient: 640 x 30 x 512B = 9.8 MB in flight.
//     Pipeline structure unchanged from R3 (counted-vmcnt A/B stages).

constexpr int B    = 32;
constexpr int T    = 16000;
constexpr int F    = 80;
constexpr int HALF = 150;          // WIN_LEN / 2
constexpr int CL   = 500;          // chunk length along t
constexpr int NCHUNK = T / CL;     // 32
constexpr int RS   = F / 2;        // row stride in float2 units = 40
constexpr int NCOL2 = B * F / 2;   // 1280 float2-columns
constexpr int NTHREADS = NCOL2 * NCHUNK;  // 40960 -> 640 waves, 2.5/CU
constexpr int BLOCK = 64;
constexpr int BT    = 10;          // rows per main pipeline stage (30 loads)
constexpr int NST   = CL / BT;     // 50 stages (even)
constexpr int WB    = 25;          // rows per warm-up stage (12 stages)

__device__ __forceinline__ void nt_store2(float2* p, float2 v) {
    union { float2 f; unsigned long long u; } c; c.f = v;
    __builtin_nontemporal_store(c.u, (unsigned long long*)p);
}
__device__ __forceinline__ float2 nt_load2(const float2* p) {
    union { unsigned long long u; float2 f; } c;
    c.u = __builtin_nontemporal_load((const unsigned long long*)p);
    return c.f;
}

__global__ __launch_bounds__(BLOCK)
__attribute__((amdgpu_waves_per_eu(1, 2)))
void slide_mean_norm(const float2* __restrict__ x, float2* __restrict__ out) {
    int tid   = blockIdx.x * BLOCK + threadIdx.x;
    int col2  = tid % NCOL2;        // consecutive lanes -> consecutive float2
    int chunk = tid / NCOL2;        // wave-uniform
    int b  = col2 / RS;
    int f2 = col2 % RS;

    const float2* xp = x   + (size_t)b * T * RS + f2;
    float2*       op = out + (size_t)b * T * RS + f2;

    int t0 = chunk * CL;
    float sx = 0.f, sy = 0.f;

    bool interior = (t0 >= HALF) && (t0 + CL - 1 + HALF <= T - 1);

    if (interior) {
        // ---- warm-up: 300 rows [t0-150, t0+150), 12 pipelined stages of 25 ----
        const float2* wp = xp + (size_t)(t0 - HALF) * RS;
        float2 wA[WB], wB[WB];
        #define WLOAD(buf, s) { const float2* p = wp + (size_t)(s) * WB * RS;       \
            _Pragma("unroll") for (int j = 0; j < WB; ++j) buf[j] = p[j * RS];      \
            __builtin_amdgcn_sched_barrier(0); }
        #define WSUM(buf) { _Pragma("unroll")                                        \
            for (int j = 0; j < WB; ++j) { sx += buf[j].x; sy += buf[j].y; } }
        WLOAD(wA, 0)
        #pragma unroll 1
        for (int r = 0; r < 10; r += 2) {
            WLOAD(wB, r + 1)
            WSUM(wA)
            WLOAD(wA, r + 2)
            WSUM(wB)
        }
        WLOAD(wB, 11)
        WSUM(wA)
        WSUM(wB)

        // ---- main: 50 pipelined stages of 10 rows (30 loads/stage) ----
        const float inv = 1.0f / (2.0f * HALF);
        float2 cA[BT], lA[BT], tA[BT], cB[BT], lB[BT], tB[BT];
        #define MLOAD(ca, la, ta, s) {                                              \
            const float2* pc = xp + (size_t)(t0 + (s) * BT) * RS;                   \
            const float2* pl = pc + HALF * RS;                                      \
            const float2* pt = pc - HALF * RS;                                      \
            _Pragma("unroll") for (int j = 0; j < BT; ++j) {                        \
                ca[j] = pc[j * RS]; la[j] = pl[j * RS]; ta[j] = nt_load2(pt + j * RS); } \
            __builtin_amdgcn_sched_barrier(0); }
        #define MCONS(ca, la, ta, s) {                                              \
            float2* po = op + (size_t)(t0 + (s) * BT) * RS;                         \
            _Pragma("unroll") for (int j = 0; j < BT; ++j) {                        \
                nt_store2(po + j * RS, make_float2(ca[j].x - sx * inv,              \
                                                   ca[j].y - sy * inv));            \
                sx += la[j].x - tA_use(ta, j).x; sy += la[j].y - tA_use(ta, j).y; } }
        #define tA_use(ta, j) ta[j]
        MLOAD(cA, lA, tA, 0)
        #pragma unroll 1
        for (int r = 0; r + 2 < NST; r += 2) {   // r = 0,2,...,46
            MLOAD(cB, lB, tB, r + 1)
            MCONS(cA, lA, tA, r)
            MLOAD(cA, lA, tA, r + 2)
            MCONS(cB, lB, tB, r + 1)
        }
        // NST even: A holds stage NST-2; stage NST-1 not yet loaded
        MLOAD(cB, lB, tB, NST - 1)
        MCONS(cA, lA, tA, NST - 2)
        MCONS(cB, lB, tB, NST - 1)
    } else {
        // ---- edge chunks (0, 31): identical pipeline, clamped + masked ----
        float2 wA[WB], wB[WB];
        #define EWLOAD(buf, s) { int kb = t0 - HALF + (s) * WB;                     \
            _Pragma("unroll") for (int j = 0; j < WB; ++j) {                        \
                int k = kb + j; int kc = k < 0 ? 0 : k;                             \
                buf[j] = xp[(size_t)kc * RS]; }                                     \
            __builtin_amdgcn_sched_barrier(0); }
        #define EWSUM(buf, s) { int kb = t0 - HALF + (s) * WB;                      \
            _Pragma("unroll") for (int j = 0; j < WB; ++j) {                        \
                float m = (kb + j >= 0) ? 1.f : 0.f;                                \
                sx += m * buf[j].x; sy += m * buf[j].y; } }
        EWLOAD(wA, 0)
        #pragma unroll 1
        for (int r = 0; r < 10; r += 2) {
            EWLOAD(wB, r + 1)
            EWSUM(wA, r)
            EWLOAD(wA, r + 2)
            EWSUM(wB, r + 1)
        }
        EWLOAD(wB, 11)
        EWSUM(wA, 10)
        EWSUM(wB, 11)

        float2 cA[BT], lA[BT], tA[BT], cB[BT], lB[BT], tB[BT];
        #define ELOAD(ca, la, ta, s) { int ib = t0 + (s) * BT;                      \
            _Pragma("unroll") for (int j = 0; j < BT; ++j) {                        \
                int t = ib + j;                                                     \
                int li = t + HALF; li = li > T - 1 ? T - 1 : li;                    \
                int ti = t - HALF; ti = ti < 0 ? 0 : ti;                            \
                ca[j] = xp[(size_t)t * RS];                                         \
                la[j] = xp[(size_t)li * RS];                                        \
                ta[j] = xp[(size_t)ti * RS]; }                                      \
            __builtin_amdgcn_sched_barrier(0); }
        #define ECONS(ca, la, ta, s) { int ib = t0 + (s) * BT;                      \
            _Pragma("unroll") for (int j = 0; j < BT; ++j) {                        \
                int t = ib + j;                                                     \
                int ss = t - HALF; ss = ss < 0 ? 0 : ss;                            \
                int ee = t + HALF; ee = ee > T - 1 ? T - 1 : ee;                    \
                float invc = 1.0f / (float)(ee - ss);                               \
                float lm = (t + HALF <= T - 2) ? 1.f : 0.f;                         \
                float tm = (t >= HALF) ? 1.f : 0.f;                                 \
                nt_store2(op + (size_t)t * RS, make_float2(ca[j].x - sx * invc,     \
                                                           ca[j].y - sy * invc));   \
                sx += lm * la[j].x - tm * ta[j].x;                                  \
                sy += lm * la[j].y - tm * ta[j].y; } }
        ELOAD(cA, lA, tA, 0)
        #pragma unroll 1
        for (int r = 0; r + 2 < NST; r += 2) {
            ELOAD(cB, lB, tB, r + 1)
            ECONS(cA, lA, tA, r)
            ELOAD(cA, lA, tA, r + 2)
            ECONS(cB, lB, tB, r + 1)
        }
        ELOAD(cB, lB, tB, NST - 1)
        ECONS(cA, lA, tA, NST - 2)
        ECONS(cB, lB, tB, NST - 1)
    }
}

extern "C" void kernel_launch(void* const* d_in, const int* in_sizes, int n_in,
                              void* d_out, int out_size, void* d_ws, size_t ws_size,
                              hipStream_t stream) {
    const float2* x = (const float2*)d_in[0];
    float2* out = (float2*)d_out;
    slide_mean_norm<<<dim3(NTHREADS / BLOCK), dim3(BLOCK), 0, stream>>>(x, out);
}

// Round 5
// 324.182 us; speedup vs baseline: 1.3862x; 1.0613x over previous
//
#include <hip/hip_runtime.h>

// SlideMean_Norm: out[b,0,t,f] = x[b,0,t,f] - mean(x[b,0,s:e,f]),
//   s = max(t-150, 0), e = min(t+150, T-1) (end-exclusive).
// R5: load-once streaming with an LDS f16 ring of the last 300 rows.
//     R3/R4 proved the 3-stream design is capped by total memory service
//     (~4.6 TB/s aggregate on 590 MB read demand); caches only absorb ~42%.
//     Now each input row is loaded ONCE per chunk (lead); center (-150) and
//     trail (-300) come from the ring. Ring slot i%300 holds row t-300..t:
//     read trail at slot, overwrite with lead, read center at slot+150.
//     f16 ring: center error <= 2.7e-3 (tolerance 1.56e-2); S uses the
//     f16-ROUNDED lead so trail subtraction cancels exactly (zero drift).
//     1 wave/block -> no barriers; DS pipe in-order per wave -> no hazards.
//     A/B pipelined stages of 32 rows keep ~32 loads in flight per wave.

constexpr int B_   = 32;
constexpr int T    = 16000;
constexpr int F    = 80;
constexpr int HALF = 150;             // WIN_LEN / 2
constexpr int WIN  = 2 * HALF;        // 300 (ring depth)
constexpr int CL   = 800;             // chunk length along t
constexpr int NCHUNK = T / CL;        // 20
constexpr int CPB  = 64;              // f32 columns per block (= lanes)
constexpr int NCOL = B_ * F;          // 2560 columns
constexpr int NCG  = NCOL / CPB;      // 40 column groups
constexpr int NBLK = NCG * NCHUNK;    // 800 blocks (1 wave each, all resident)
constexpr int D    = 32;              // rows per main pipeline stage
constexpr int NST  = CL / D;          // 25 (odd)
constexpr int WD   = 30;              // rows per warm-up stage
constexpr int WNST = WIN / WD;        // 10

__global__ __launch_bounds__(64)
__attribute__((amdgpu_waves_per_eu(1, 2)))
void slide_mean_norm(const float* __restrict__ x, float* __restrict__ out) {
    __shared__ _Float16 ring[WIN * CPB];   // [slot][lane], 38400 B, 4 blocks/CU

    const int lane  = threadIdx.x;
    const int bid   = blockIdx.x;
    const int cg    = bid % NCG;           // adjacent blocks -> adjacent columns
    const int chunk = bid / NCG;
    const int col   = cg * CPB + lane;
    const int b     = col / F;
    const int f     = col % F;
    const size_t cbase = (size_t)b * T * F + f;
    const float* xp = x + cbase;
    float*       op = out + cbase;
    const int t0 = chunk * CL;

    float S = 0.f;

    // ---------------- warm-up: rows [t0-150, t0+150) -> ring + S ----------------
    float wA[WD], wB[WD];
    auto WLOAD = [&](float (&buf)[WD], int ws) {
        int r0 = t0 - HALF + ws * WD;
        #pragma unroll
        for (int j = 0; j < WD; ++j) {
            int r = r0 + j; if (r < 0) r = 0;      // clamp (chunk 0 only)
            buf[j] = xp[(size_t)r * F];
        }
        __builtin_amdgcn_sched_barrier(0);
    };
    auto WCONS = [&](float (&buf)[WD], int ws) {
        int r0 = t0 - HALF + ws * WD;
        int k0 = ws * WD;                          // ring slot base
        #pragma unroll
        for (int j = 0; j < WD; ++j) {
            _Float16 h = (_Float16)buf[j];
            ring[(k0 + j) * CPB + lane] = h;
            float v = (float)h;                    // rounded value -> exact cancel
            S += (r0 + j >= 0) ? v : 0.f;          // mask rows < 0 (chunk 0)
        }
    };
    WLOAD(wA, 0);
    #pragma unroll 1
    for (int r = 0; r + 2 < WNST; r += 2) {
        WLOAD(wB, r + 1);
        WCONS(wA, r);
        WLOAD(wA, r + 2);
        WCONS(wB, r + 1);
    }
    WLOAD(wB, WNST - 1);
    WCONS(wA, WNST - 2);
    WCONS(wB, WNST - 1);

    // ---------------- main: CL rows, A/B stages of D, 1 load/row ----------------
    float mA[D], mB[D];
    auto LOAD = [&](float (&buf)[D], int ss) {
        int r0 = t0 + ss * D + HALF;               // lead row = t + 150
        #pragma unroll
        for (int j = 0; j < D; ++j) {
            int r = r0 + j; if (r > T - 1) r = T - 1;  // clamp (last chunk only)
            buf[j] = xp[(size_t)r * F];
        }
        __builtin_amdgcn_sched_barrier(0);
    };
    auto CONS = [&](float (&buf)[D], int cs) {
        int i0 = cs * D;
        int sb = i0;        sb -= (sb >= 600) ? 600 : 0; sb -= (sb >= 300) ? 300 : 0;
        int cb = i0 + HALF; cb -= (cb >= 600) ? 600 : 0; cb -= (cb >= 300) ? 300 : 0;
        int tb = t0 + i0;
        float tr[D], ce[D], lr[D];
        // phase R: all ring reads (before any write this stage)
        #pragma unroll
        for (int j = 0; j < D; ++j) {
            int sl = sb + j; if (sl >= WIN) sl -= WIN;
            int cc = cb + j; if (cc >= WIN) cc -= WIN;
            tr[j] = (float)ring[sl * CPB + lane];   // x[t-150] (f16)
            ce[j] = (float)ring[cc * CPB + lane];   // x[t]     (f16)
        }
        // phase W: overwrite trail slots with fresh lead
        #pragma unroll
        for (int j = 0; j < D; ++j) {
            int sl = sb + j; if (sl >= WIN) sl -= WIN;
            _Float16 h = (_Float16)buf[j];
            ring[sl * CPB + lane] = h;
            lr[j] = (float)h;                       // rounded lead for S
        }
        // phase C: outputs + running-sum update (serial chain on S only)
        #pragma unroll
        for (int j = 0; j < D; ++j) {
            int t  = tb + j;                        // wave-uniform
            int s_ = t - HALF; if (s_ < 0) s_ = 0;
            int e_ = t + HALF; if (e_ > T - 1) e_ = T - 1;
            float inv = __fdividef(1.0f, (float)(e_ - s_));
            float o = ce[j] - S * inv;
            __builtin_nontemporal_store(o, op + (size_t)t * F);
            float a = (t <= T - 2 - HALF) ? lr[j] : 0.f;   // add x[t+150] iff in range
            float d = (t >= HALF)         ? tr[j] : 0.f;   // sub x[t-150] iff in range
            S += a - d;
        }
    };
    LOAD(mA, 0);
    #pragma unroll 1
    for (int s = 0; s + 2 < NST; s += 2) {          // s = 0,2,...,22
        LOAD(mB, s + 1);
        CONS(mA, s);
        LOAD(mA, s + 2);
        CONS(mB, s + 1);
    }
    CONS(mA, NST - 1);                              // NST odd: A holds stage 24
}

extern "C" void kernel_launch(void* const* d_in, const int* in_sizes, int n_in,
                              void* d_out, int out_size, void* d_ws, size_t ws_size,
                              hipStream_t stream) {
    const float* x = (const float*)d_in[0];
    float* out = (float*)d_out;
    slide_mean_norm<<<dim3(NBLK), dim3(64), 0, stream>>>(x, out);
}